// Round 5
// baseline (114.274 us; speedup 1.0000x reference)
//
#include <hip/hip_runtime.h>

#define DIM 6
#define NSEG 65535
#define CH 32            // segments per chunk
#define NCHUNK 2048      // NCHUNK*CH >= NSEG

// Padded partial-signature layout (per chunk), stride in floats.
// 16B-aligned sections: L1@0(6), L2@8(36), L3@48(216), L4@264(1296)
#define PSTRIDE 1568
#define PL1 0
#define PL2 8
#define PL3 48
#define PL4 264

// ---------------- Kernel 1: one wave per chunk, register-resident Chen fold -
// Lane t<36 owns pair ab=t (a=ab/6, b=ab%6): S4 row (36 regs), S3 row (6),
// S2[ab] (1), private S1[a] (1).  No dynamic indexing of register arrays:
// lane-dependent dx_a/dx_b come from lane-addressed LDS reads.
__global__ __launch_bounds__(64) void sig_fold(const float* __restrict__ x,
                                               float* __restrict__ part) {
    __shared__ float dxs[CH * 8];   // dx row j at 8-float stride
    const int t = threadIdx.x;
    const int c = blockIdx.x;
    const int j0 = c * CH;
    const int cnt = min(CH, NSEG - j0);    // 32, or 31 for the last chunk

    for (int f = t; f < CH * 8; f += 64) dxs[f] = 0.f;
    __syncthreads();
    const float* xb = x + (size_t)j0 * DIM;
    for (int f = t; f < cnt * DIM; f += 64) {
        int j = f / 6, k = f - j * 6;
        dxs[j * 8 + k] = xb[f + 6] - xb[f];
    }
    __syncthreads();

    const int ab = (t < 36) ? t : 35;
    const int a = ab / 6, b = ab - a * 6;
    const float* dxap = dxs + a;    // lane-varying LDS bases
    const float* dxbp = dxs + b;

    float r4[36], r3[6], r2 = 0.f, s1 = 0.f;
#pragma unroll
    for (int i = 0; i < 36; ++i) r4[i] = 0.f;
#pragma unroll
    for (int i = 0; i < 6; ++i) r3[i] = 0.f;

#pragma unroll 2
    for (int j = 0; j < CH; ++j) {
        const float4 q0 = *(const float4*)(dxs + j * 8);
        const float2 q1 = *(const float2*)(dxs + j * 8 + 4);
        const float dxv[6] = {q0.x, q0.y, q0.z, q0.w, q1.x, q1.y}; // const-idx only
        const float dxa = dxap[j * 8];   // ds_read lane-addressed
        const float dxb = dxbp[j * 8];

        // t2 = S2 + dx_b*(S1/3 + dx_a/12)            (old S2, S1)
        float t2 = fmaf(dxb, fmaf(dxa, (1.f / 12.f), s1 * (1.f / 3.f)), r2);
        float t2h = 0.5f * t2;
        // S4[cd] += (S3[c] + t2*0.5*dx[c]) * dx[d]   (old S3)
        float w[6];
#pragma unroll
        for (int cc = 0; cc < 6; ++cc) w[cc] = fmaf(t2h, dxv[cc], r3[cc]);
#pragma unroll
        for (int cc = 0; cc < 6; ++cc)
#pragma unroll
            for (int d = 0; d < 6; ++d)
                r4[cc * 6 + d] = fmaf(w[cc], dxv[d], r4[cc * 6 + d]);
        // S3[c] += (S2 + t3*0.5*dx_b) * dx[c],  t3 = S1 + dx_a/3
        float t3 = fmaf(dxa, (1.f / 3.f), s1);
        float v = fmaf(0.5f * t3, dxb, r2);
#pragma unroll
        for (int cc = 0; cc < 6; ++cc) r3[cc] = fmaf(v, dxv[cc], r3[cc]);
        // S2 += (S1 + 0.5*dx_a) * dx_b ; S1 += dx_a
        r2 = fmaf(fmaf(0.5f, dxa, s1), dxb, r2);
        s1 += dxa;
    }

    if (t < 36) {
        float* P = part + (size_t)c * PSTRIDE;
        if (a == b) P[PL1 + a] = s1;
        P[PL2 + ab] = r2;
        float* p3 = P + PL3 + ab * 6;
        *(float2*)(p3 + 0) = make_float2(r3[0], r3[1]);
        *(float2*)(p3 + 2) = make_float2(r3[2], r3[3]);
        *(float2*)(p3 + 4) = make_float2(r3[4], r3[5]);
        float* p4 = P + PL4 + ab * 36;
#pragma unroll
        for (int i = 0; i < 9; ++i)
            *(float4*)(p4 + 4 * i) =
                make_float4(r4[4 * i], r4[4 * i + 1], r4[4 * i + 2], r4[4 * i + 3]);
    }
}

// ---------------- Kernel 2: register-resident sequential Chen combine -------
// Block g folds partials [g*R, (g+1)*R): Acc = Acc (x) U_r.  Lane ab owns
// T4 row ab (36), T3 row ab (6), T2[ab], S1[a].  Every lane-dependent B
// operand is a MEMORY load with a lane-computed address (never a dynamic
// index into a register array); all register arrays are const-indexed in
// fully unrolled loops -> no scratch.
__global__ __launch_bounds__(64) void sig_comb(const float* __restrict__ in,
                                               float* __restrict__ out,
                                               int R, int flat_out) {
    const int t = threadIdx.x;
    const int ab = (t < 36) ? t : 35;
    const int a = ab / 6, b = ab - a * 6;
    const float* base = in + (size_t)blockIdx.x * R * PSTRIDE;

    float r4[36], r3[6], r2, s1;
    {
        const float* P = base;
        s1 = P[PL1 + a];
        r2 = P[PL2 + ab];
        const float* p3 = P + PL3 + ab * 6;   // 8B-aligned
#pragma unroll
        for (int i = 0; i < 3; ++i) {
            float2 q = *(const float2*)(p3 + 2 * i);
            r3[2 * i] = q.x; r3[2 * i + 1] = q.y;
        }
        const float* p4 = P + PL4 + ab * 36;  // 16B-aligned
#pragma unroll
        for (int i = 0; i < 9; ++i) {
            float4 q = *(const float4*)(p4 + 4 * i);
            r4[4 * i] = q.x; r4[4 * i + 1] = q.y;
            r4[4 * i + 2] = q.z; r4[4 * i + 3] = q.w;
        }
    }

    for (int r = 1; r < R; ++r) {
        const float* U = base + (size_t)r * PSTRIDE;
        // uniform operands (same address on every lane)
        float b1[6];
#pragma unroll
        for (int d = 0; d < 6; ++d) b1[d] = U[PL1 + d];
        float b2[36];
#pragma unroll
        for (int i = 0; i < 9; ++i) {
            float4 q = *(const float4*)(U + PL2 + 4 * i);
            b2[4 * i] = q.x; b2[4 * i + 1] = q.y;
            b2[4 * i + 2] = q.z; b2[4 * i + 3] = q.w;
        }
        // lane-dependent operands: loads at computed addresses
        float b1a = U[PL1 + a];
        float b1b = U[PL1 + b];
        float b2ab = U[PL2 + ab];
        float b2rb[6];                         // B2 row b
        {
            const float* p = U + PL2 + b * 6;  // 8B-aligned (b*6 even)
#pragma unroll
            for (int i = 0; i < 3; ++i) {
                float2 q = *(const float2*)(p + 2 * i);
                b2rb[2 * i] = q.x; b2rb[2 * i + 1] = q.y;
            }
        }
        float b3ab[6];                         // B3 row ab
        {
            const float* p = U + PL3 + ab * 6;
#pragma unroll
            for (int i = 0; i < 3; ++i) {
                float2 q = *(const float2*)(p + 2 * i);
                b3ab[2 * i] = q.x; b3ab[2 * i + 1] = q.y;
            }
        }
        float b3b[36];                         // B3 block row b (36)
        {
            const float* p = U + PL3 + b * 36; // 16B-aligned
#pragma unroll
            for (int i = 0; i < 9; ++i) {
                float4 q = *(const float4*)(p + 4 * i);
                b3b[4 * i] = q.x; b3b[4 * i + 1] = q.y;
                b3b[4 * i + 2] = q.z; b3b[4 * i + 3] = q.w;
            }
        }
        float b4[36];                          // B4 row ab (36)
        {
            const float* p = U + PL4 + ab * 36;
#pragma unroll
            for (int i = 0; i < 9; ++i) {
                float4 q = *(const float4*)(p + 4 * i);
                b4[4 * i] = q.x; b4[4 * i + 1] = q.y;
                b4[4 * i + 2] = q.z; b4[4 * i + 3] = q.w;
            }
        }

        // T4 (old r3, r2, s1)
#pragma unroll
        for (int cc = 0; cc < 6; ++cc)
#pragma unroll
            for (int d = 0; d < 6; ++d) {
                const int cd = cc * 6 + d;
                float v = r4[cd] + b4[cd];
                v = fmaf(r3[cc], b1[d], v);
                v = fmaf(r2, b2[cd], v);
                r4[cd] = fmaf(s1, b3b[cd], v);
            }
        // T3 (old r2, s1)
#pragma unroll
        for (int cc = 0; cc < 6; ++cc) {
            float v = r3[cc] + b3ab[cc];
            v = fmaf(r2, b1[cc], v);
            r3[cc] = fmaf(s1, b2rb[cc], v);
        }
        // T2, T1 (old s1)
        r2 = fmaf(s1, b1b, r2 + b2ab);
        s1 += b1a;
    }

    if (t < 36) {
        if (flat_out) {
            float* O = out;               // flat 1554: L1@0 L2@6 L3@42 L4@258
            if (a == b) O[a] = s1;
            O[6 + ab] = r2;
            float* o3 = O + 42 + ab * 6;
#pragma unroll
            for (int i = 0; i < 3; ++i)
                *(float2*)(o3 + 2 * i) = make_float2(r3[2 * i], r3[2 * i + 1]);
            float* o4 = O + 258 + ab * 36;    // 8B-aligned
#pragma unroll
            for (int i = 0; i < 18; ++i)
                *(float2*)(o4 + 2 * i) = make_float2(r4[2 * i], r4[2 * i + 1]);
        } else {
            float* P = out + (size_t)blockIdx.x * PSTRIDE;
            if (a == b) P[PL1 + a] = s1;
            P[PL2 + ab] = r2;
            float* p3 = P + PL3 + ab * 6;
#pragma unroll
            for (int i = 0; i < 3; ++i)
                *(float2*)(p3 + 2 * i) = make_float2(r3[2 * i], r3[2 * i + 1]);
            float* p4 = P + PL4 + ab * 36;
#pragma unroll
            for (int i = 0; i < 9; ++i)
                *(float4*)(p4 + 4 * i) =
                    make_float4(r4[4 * i], r4[4 * i + 1], r4[4 * i + 2], r4[4 * i + 3]);
        }
    }
}

// ---------------------------------------------------------------------------
extern "C" void kernel_launch(void* const* d_in, const int* in_sizes, int n_in,
                              void* d_out, int out_size, void* d_ws, size_t ws_size,
                              hipStream_t stream) {
    const float* x = (const float*)d_in[0];
    float* out = (float*)d_out;
    float* ws0 = (float*)d_ws;                          // 2048 padded partials
    float* ws1 = ws0 + (size_t)NCHUNK * PSTRIDE;        // 256
    float* ws2 = ws1 + (size_t)256 * PSTRIDE;           // 16

    sig_fold<<<NCHUNK, 64, 0, stream>>>(x, ws0);
    sig_comb<<<256, 64, 0, stream>>>(ws0, ws1, 8, 0);   // 2048 -> 256
    sig_comb<<<16, 64, 0, stream>>>(ws1, ws2, 16, 0);   // 256  -> 16
    sig_comb<<<1, 64, 0, stream>>>(ws2, out, 16, 1);    // 16   -> 1
}